// Round 3
// baseline (784.148 us; speedup 1.0000x reference)
//
#include <hip/hip_runtime.h>
#include <hip/hip_bf16.h>

typedef __hip_bfloat16 bf16;
typedef unsigned short u16t;
typedef unsigned int u32t;

#define DEVI static __device__ __forceinline__

DEVI float u2f(u32t bits) { union { u32t u; float f; } v; v.u = bits; return v.f; }
DEVI float bflo(u32t u) { return u2f((u & 0xffffu) << 16); }
DEVI float bfhi(u32t u) { return u2f(u & 0xffff0000u); }
DEVI float bf2f(bf16 h) { return __bfloat162float(h); }
DEVI bf16 f2bf(float f) { return __float2bfloat16(f); }
DEVI u16t f2bfbits(float f) {
  bf16 h = __float2bfloat16(f);
  union { bf16 h; u16t u; } v; v.h = h; return v.u;
}

// Problem constants: x (2,8,56,56,128); windows (2,7,7) -> N=98; NW=512
#define TOK   50176
#define NWIN  512
#define NTOK  98
#define NHEAD 4
#define HDIM  32

// ---------------------------------------------------------------------------
// LN1 (fp32 input, token order) + window partition -> bf16
// One wave per token, 2 channels/lane (C=128).
// ---------------------------------------------------------------------------
__global__ __launch_bounds__(256) void ln1_k(
    const float* __restrict__ x, const float* __restrict__ w,
    const float* __restrict__ b, bf16* __restrict__ o)
{
  const int wave = threadIdx.x >> 6, lane = threadIdx.x & 63;
  const int t = blockIdx.x * 4 + wave;
  const int c = lane << 1;
  float2 xv = *(const float2*)(x + (size_t)t * 128 + c);
  float x0 = xv.x, x1 = xv.y;
  float s = x0 + x1, ss = x0 * x0 + x1 * x1;
#pragma unroll
  for (int m = 32; m; m >>= 1) { s += __shfl_xor(s, m); ss += __shfl_xor(ss, m); }
  float mean = s * 0.0078125f;
  float var = ss * 0.0078125f - mean * mean;
  float rstd = rsqrtf(var + 1e-5f);
  float y0 = (x0 - mean) * rstd * w[c]     + b[c];
  float y1 = (x1 - mean) * rstd * w[c + 1] + b[c + 1];
  // token t=(bi,di,hi,wi) -> window nw, intra-window n
  int wi = t % 56; int r = t / 56;
  int hi_ = r % 56; r /= 56;
  int di = r & 7; int bi = r >> 3;
  int nw = ((bi * 4 + (di >> 1)) * 8 + hi_ / 7) * 8 + wi / 7;
  int n  = ((di & 1) * 7 + hi_ % 7) * 7 + wi % 7;
  u32t ov = ((u32t)f2bfbits(y1) << 16) | (u32t)f2bfbits(y0);
  *(u32t*)((u16t*)o + (size_t)(nw * NTOK + n) * 128 + c) = ov;
}

// ---------------------------------------------------------------------------
// LN2 (bf16 input, token order) -> bf16
// ---------------------------------------------------------------------------
__global__ __launch_bounds__(256) void ln2_k(
    const bf16* __restrict__ x, const float* __restrict__ w,
    const float* __restrict__ b, bf16* __restrict__ o)
{
  const int wave = threadIdx.x >> 6, lane = threadIdx.x & 63;
  const int t = blockIdx.x * 4 + wave;
  const int c = lane << 1;
  u32t u = *(const u32t*)((const u16t*)x + (size_t)t * 128 + c);
  float x0 = bflo(u), x1 = bfhi(u);
  float s = x0 + x1, ss = x0 * x0 + x1 * x1;
#pragma unroll
  for (int m = 32; m; m >>= 1) { s += __shfl_xor(s, m); ss += __shfl_xor(ss, m); }
  float mean = s * 0.0078125f;
  float var = ss * 0.0078125f - mean * mean;
  float rstd = rsqrtf(var + 1e-5f);
  float y0 = (x0 - mean) * rstd * w[c]     + b[c];
  float y1 = (x1 - mean) * rstd * w[c + 1] + b[c + 1];
  u32t ov = ((u32t)f2bfbits(y1) << 16) | (u32t)f2bfbits(y0);
  *(u32t*)((u16t*)o + (size_t)t * 128 + c) = ov;
}

// ---------------------------------------------------------------------------
// Tiled GEMM: C[M,N] = A[M,K](bf16) @ Wt[N,K](fp32)^T + bias(fp32).
// 64x64 tile, BK=32, 256 threads, 4x4 microtile, fp32 accumulation.
// MODE 0: + bias -> bf16                              (qkv)
// MODE 1: + bias + window-reverse + residual(fp32 x)  -> bf16 (proj)
// MODE 2: + bias + exact GELU -> bf16                 (fc1)
// MODE 3: + bias + residual(bf16 x2) -> fp32 out      (fc2, final)
// ---------------------------------------------------------------------------
template <int MODE>
__global__ __launch_bounds__(256) void gemm_k(
    const bf16* __restrict__ A, const float* __restrict__ Wt,
    const float* __restrict__ bias, const float* __restrict__ resX,
    const bf16* __restrict__ resB2, bf16* __restrict__ outB,
    float* __restrict__ outF, int N, int K)
{
  __shared__ float As[64][33];
  __shared__ float Bs[64][33];
  const int tid = threadIdx.x;
  const int rowBase = blockIdx.y << 6;
  const int colBase = blockIdx.x << 6;
  const int tx = tid & 15, ty = tid >> 4;
  const int lr = tid >> 2;          // staging row 0..63
  const int lc = (tid & 3) << 3;    // staging col chunk (8 elems)
  float acc[4][4] = {};

  const u16t*  Ap = (const u16t*)A + (size_t)(rowBase + lr) * K + lc;
  const float* Wp = Wt + (size_t)(colBase + lr) * K + lc;

  for (int k0 = 0; k0 < K; k0 += 32) {
    uint4 ua = *(const uint4*)(Ap + k0);
    float4 w0 = *(const float4*)(Wp + k0);
    float4 w1 = *(const float4*)(Wp + k0 + 4);
    float* da = &As[lr][lc];
    da[0] = bflo(ua.x); da[1] = bfhi(ua.x); da[2] = bflo(ua.y); da[3] = bfhi(ua.y);
    da[4] = bflo(ua.z); da[5] = bfhi(ua.z); da[6] = bflo(ua.w); da[7] = bfhi(ua.w);
    float* db = &Bs[lr][lc];
    db[0] = w0.x; db[1] = w0.y; db[2] = w0.z; db[3] = w0.w;
    db[4] = w1.x; db[5] = w1.y; db[6] = w1.z; db[7] = w1.w;
    __syncthreads();
#pragma unroll
    for (int kk = 0; kk < 32; kk++) {
      float a0 = As[(ty << 2) + 0][kk];
      float a1 = As[(ty << 2) + 1][kk];
      float a2 = As[(ty << 2) + 2][kk];
      float a3 = As[(ty << 2) + 3][kk];
      float b0 = Bs[(tx << 2) + 0][kk];
      float b1 = Bs[(tx << 2) + 1][kk];
      float b2 = Bs[(tx << 2) + 2][kk];
      float b3 = Bs[(tx << 2) + 3][kk];
      acc[0][0] += a0 * b0; acc[0][1] += a0 * b1; acc[0][2] += a0 * b2; acc[0][3] += a0 * b3;
      acc[1][0] += a1 * b0; acc[1][1] += a1 * b1; acc[1][2] += a1 * b2; acc[1][3] += a1 * b3;
      acc[2][0] += a2 * b0; acc[2][1] += a2 * b1; acc[2][2] += a2 * b2; acc[2][3] += a2 * b3;
      acc[3][0] += a3 * b0; acc[3][1] += a3 * b1; acc[3][2] += a3 * b2; acc[3][3] += a3 * b3;
    }
    __syncthreads();
  }

  float bv[4];
#pragma unroll
  for (int j = 0; j < 4; j++) bv[j] = bias[colBase + (tx << 2) + j];

#pragma unroll
  for (int i = 0; i < 4; i++) {
    int row = rowBase + (ty << 2) + i;
    if (MODE == 1) {
      // window-reverse: row = nw*98+n  ->  token index t
      int nw = row / NTOK, n = row - nw * NTOK;
      int wq = nw & 7, hq = (nw >> 3) & 7, dq = (nw >> 6) & 3, bb = nw >> 8;
      int wr = n % 7; int q7 = n / 7; int hr = q7 % 7, dr = q7 / 7;
      int t = ((bb * 8 + dq * 2 + dr) * 56 + hq * 7 + hr) * 56 + wq * 7 + wr;
      size_t ob = (size_t)t * 128;
#pragma unroll
      for (int j = 0; j < 4; j++) {
        int col = colBase + (tx << 2) + j;
        outB[ob + col] = f2bf(acc[i][j] + bv[j] + resX[ob + col]);
      }
    } else if (MODE == 2) {
      size_t ob = (size_t)row * N;
#pragma unroll
      for (int j = 0; j < 4; j++) {
        int col = colBase + (tx << 2) + j;
        float u = acc[i][j] + bv[j];
        float g = 0.5f * u * (1.0f + erff(u * 0.70710678118654752f));
        outB[ob + col] = f2bf(g);
      }
    } else if (MODE == 3) {
      size_t ob = (size_t)row * N;
#pragma unroll
      for (int j = 0; j < 4; j++) {
        int col = colBase + (tx << 2) + j;
        outF[ob + col] = acc[i][j] + bv[j] + bf2f(resB2[ob + col]);
      }
    } else {
      size_t ob = (size_t)row * N;
#pragma unroll
      for (int j = 0; j < 4; j++) {
        int col = colBase + (tx << 2) + j;
        outB[ob + col] = f2bf(acc[i][j] + bv[j]);
      }
    }
  }
}

// ---------------------------------------------------------------------------
// Fused windowed attention. One block per (window, head). q,k,v in LDS;
// 4 waves each own one query row per iteration; uniform 25-iteration loop
// with __syncthreads() separating softmax-p write from PV read.
// ---------------------------------------------------------------------------
__global__ __launch_bounds__(256) void attn_k(
    const bf16* __restrict__ qkv, const float* __restrict__ btab,
    const int* __restrict__ relidx, bf16* __restrict__ out)
{
  __shared__ float qs[NTOK][32];
  __shared__ float ks[NTOK][33];
  __shared__ float vs[NTOK][33];
  __shared__ float ps[4][104];
  const int nw = blockIdx.x, head = blockIdx.y;
  const int tid = threadIdx.x;
  const float scale = 0.17677669529663687f;  // 32^-0.5

  for (int idx = tid; idx < NTOK * 32; idx += 256) {
    int r = idx >> 5, d = idx & 31;
    size_t base = (size_t)(nw * NTOK + r) * 384 + head * 32 + d;
    qs[r][d] = bf2f(qkv[base]) * scale;
    ks[r][d] = bf2f(qkv[base + 128]);
    vs[r][d] = bf2f(qkv[base + 256]);
  }
  __syncthreads();

  const int wave = tid >> 6, lane = tid & 63;
  const int j0 = lane;
  const bool vld1 = lane < 34;            // lane+64 < 98
  const int j1 = vld1 ? lane + 64 : NTOK - 1;
  const int dd = lane & 31, half = lane >> 5;

  for (int it = 0; it < 25; it++) {       // uniform trip count for barriers
    int i = it * 4 + wave;
    bool act = i < NTOK;
    int ii = act ? i : 0;
    float s0 = 0.f, s1 = 0.f;
#pragma unroll
    for (int d = 0; d < 32; d++) {
      float qv = qs[ii][d];
      s0 += qv * ks[j0][d];
      s1 += qv * ks[j1][d];
    }
    s0 += btab[relidx[ii * NTOK + j0] * NHEAD + head];
    float b1 = btab[relidx[ii * NTOK + j1] * NHEAD + head];
    s1 = vld1 ? (s1 + b1) : -1.0e30f;
    float m = fmaxf(s0, s1);
#pragma unroll
    for (int d = 32; d; d >>= 1) m = fmaxf(m, __shfl_xor(m, d));
    float e0 = __expf(s0 - m);
    float e1 = vld1 ? __expf(s1 - m) : 0.f;
    float sum = e0 + e1;
#pragma unroll
    for (int d = 32; d; d >>= 1) sum += __shfl_xor(sum, d);
    float inv = 1.f / sum;
    ps[wave][j0] = e0 * inv;
    if (vld1) ps[wave][lane + 64] = e1 * inv;
    __syncthreads();
    // PV: lane halves split j-range (49 each), combine via shfl
    float a = 0.f;
#pragma unroll
    for (int jj = 0; jj < 49; jj++) {
      int j = half * 49 + jj;
      a += ps[wave][j] * vs[j][dd];
    }
    a += __shfl_down(a, 32);
    if (act && lane < 32)
      out[(size_t)(nw * NTOK + i) * 128 + head * 32 + dd] = f2bf(a);
    __syncthreads();
  }
}

// ---------------------------------------------------------------------------
extern "C" void kernel_launch(void* const* d_in, const int* in_sizes, int n_in,
                              void* d_out, int out_size, void* d_ws, size_t ws_size,
                              hipStream_t stream) {
  const float* x      = (const float*)d_in[0];
  const float* n1w    = (const float*)d_in[1];
  const float* n1b    = (const float*)d_in[2];
  const float* qkv_w  = (const float*)d_in[3];
  const float* qkv_b  = (const float*)d_in[4];
  const float* btab   = (const float*)d_in[5];
  const float* proj_w = (const float*)d_in[6];
  const float* proj_b = (const float*)d_in[7];
  const float* n2w    = (const float*)d_in[8];
  const float* n2b    = (const float*)d_in[9];
  const float* fc1_w  = (const float*)d_in[10];
  const float* fc1_b  = (const float*)d_in[11];
  const float* fc2_w  = (const float*)d_in[12];
  const float* fc2_b  = (const float*)d_in[13];
  const int*   relidx = (const int*)d_in[14];

  // Buffer plan (A = 50176*128*2 = 12,845,056 B of bf16):
  //   d_out (2A bytes as fp32 output) doubles as scratch until the final write:
  //     xw   = d_out[0,A)   (LN1 partitioned; dead after qkv gemm)
  //     attn = d_out[0,A)   (attention output; dead after proj gemm)
  //   ws peak usage = 3A = 38.5 MB:
  //     qkv  = ws[0,3A)     (dead after attn_k)
  //     x2   = ws[0,A)      (post-attn residual stream, bf16)
  //     xn2  = ws[A,2A)
  //     hmid = ws[2A,3A)    (MLP chunk buffer, 12544 x 512 bf16)
  const size_t Asz = (size_t)TOK * 128 * 2;
  char* ws = (char*)d_ws;
  bf16* xw    = (bf16*)d_out;
  bf16* attn  = (bf16*)d_out;
  bf16* qkv   = (bf16*)(ws);
  bf16* x2    = (bf16*)(ws);
  bf16* xn2   = (bf16*)(ws + Asz);
  bf16* hmid  = (bf16*)(ws + 2 * Asz);
  float* out  = (float*)d_out;

  // 1. LN1 + window partition
  ln1_k<<<TOK / 4, 256, 0, stream>>>(x, n1w, n1b, xw);
  // 2. QKV: (50176,128) @ (384,128)^T
  gemm_k<0><<<dim3(6, TOK / 64), 256, 0, stream>>>(
      xw, qkv_w, qkv_b, nullptr, nullptr, qkv, nullptr, 384, 128);
  // 3. windowed attention (reads qkv in ws, writes attn in d_out)
  attn_k<<<dim3(NWIN, NHEAD), 256, 0, stream>>>(qkv, btab, relidx, attn);
  // 4. proj + window reverse + residual(x fp32) -> x2 bf16 (token order)
  gemm_k<1><<<dim3(2, TOK / 64), 256, 0, stream>>>(
      attn, proj_w, proj_b, x, nullptr, x2, nullptr, 128, 128);
  // 5. LN2
  ln2_k<<<TOK / 4, 256, 0, stream>>>(x2, n2w, n2b, xn2);
  // 6/7. MLP in 4 token chunks (hmid reuse keeps ws at 3A)
  const int MC = TOK / 4;  // 12544 rows per chunk
  for (int c = 0; c < 4; c++) {
    gemm_k<2><<<dim3(8, MC / 64), 256, 0, stream>>>(
        xn2 + (size_t)c * MC * 128, fc1_w, fc1_b, nullptr, nullptr,
        hmid, nullptr, 512, 128);
    gemm_k<3><<<dim3(2, MC / 64), 256, 0, stream>>>(
        hmid, fc2_w, fc2_b, nullptr, x2 + (size_t)c * MC * 128,
        nullptr, out + (size_t)c * MC * 128, 128, 512);
  }
}

// Round 4
// 401.059 us; speedup vs baseline: 1.9552x; 1.9552x over previous
//
#include <hip/hip_runtime.h>
#include <hip/hip_bf16.h>

typedef __hip_bfloat16 bf16;
typedef unsigned short u16t;
typedef unsigned int u32t;
typedef __attribute__((ext_vector_type(8))) short bf16x8_t;
typedef __attribute__((ext_vector_type(4))) float f32x4_t;

#define DEVI static __device__ __forceinline__

DEVI float u2f(u32t bits) { union { u32t u; float f; } v; v.u = bits; return v.f; }
DEVI float bflo(u32t u) { return u2f((u & 0xffffu) << 16); }
DEVI float bfhi(u32t u) { return u2f(u & 0xffff0000u); }
DEVI float bf2f(bf16 h) { return __bfloat162float(h); }
DEVI bf16 f2bf(float f) { return __float2bfloat16(f); }
DEVI u16t f2bfbits(float f) {
  bf16 h = __float2bfloat16(f);
  union { bf16 h; u16t u; } v; v.h = h; return v.u;
}

// Problem constants: x (2,8,56,56,128); windows (2,7,7) -> N=98; NW=512
#define TOK   50176
#define NWIN  512
#define NTOK  98
#define NHEAD 4
#define HDIM  32

// ---------------------------------------------------------------------------
// fp32 -> bf16 weight conversion
// ---------------------------------------------------------------------------
__global__ __launch_bounds__(256) void cvt_k(const float* __restrict__ s,
                                             bf16* __restrict__ d, int n) {
  int i = blockIdx.x * 256 + threadIdx.x;
  if (i < n) d[i] = f2bf(s[i]);
}

// ---------------------------------------------------------------------------
// LN1 (fp32 input, token order) + window partition -> bf16
// ---------------------------------------------------------------------------
__global__ __launch_bounds__(256) void ln1_k(
    const float* __restrict__ x, const float* __restrict__ w,
    const float* __restrict__ b, bf16* __restrict__ o)
{
  const int wave = threadIdx.x >> 6, lane = threadIdx.x & 63;
  const int t = blockIdx.x * 4 + wave;
  const int c = lane << 1;
  float2 xv = *(const float2*)(x + (size_t)t * 128 + c);
  float x0 = xv.x, x1 = xv.y;
  float s = x0 + x1, ss = x0 * x0 + x1 * x1;
#pragma unroll
  for (int m = 32; m; m >>= 1) { s += __shfl_xor(s, m); ss += __shfl_xor(ss, m); }
  float mean = s * 0.0078125f;
  float var = ss * 0.0078125f - mean * mean;
  float rstd = rsqrtf(var + 1e-5f);
  float y0 = (x0 - mean) * rstd * w[c]     + b[c];
  float y1 = (x1 - mean) * rstd * w[c + 1] + b[c + 1];
  int wi = t % 56; int r = t / 56;
  int hi_ = r % 56; r /= 56;
  int di = r & 7; int bi = r >> 3;
  int nw = ((bi * 4 + (di >> 1)) * 8 + hi_ / 7) * 8 + wi / 7;
  int n  = ((di & 1) * 7 + hi_ % 7) * 7 + wi % 7;
  u32t ov = ((u32t)f2bfbits(y1) << 16) | (u32t)f2bfbits(y0);
  *(u32t*)((u16t*)o + (size_t)(nw * NTOK + n) * 128 + c) = ov;
}

// ---------------------------------------------------------------------------
// LN2 (bf16 input, token order) -> bf16
// ---------------------------------------------------------------------------
__global__ __launch_bounds__(256) void ln2_k(
    const bf16* __restrict__ x, const float* __restrict__ w,
    const float* __restrict__ b, bf16* __restrict__ o)
{
  const int wave = threadIdx.x >> 6, lane = threadIdx.x & 63;
  const int t = blockIdx.x * 4 + wave;
  const int c = lane << 1;
  u32t u = *(const u32t*)((const u16t*)x + (size_t)t * 128 + c);
  float x0 = bflo(u), x1 = bfhi(u);
  float s = x0 + x1, ss = x0 * x0 + x1 * x1;
#pragma unroll
  for (int m = 32; m; m >>= 1) { s += __shfl_xor(s, m); ss += __shfl_xor(ss, m); }
  float mean = s * 0.0078125f;
  float var = ss * 0.0078125f - mean * mean;
  float rstd = rsqrtf(var + 1e-5f);
  float y0 = (x0 - mean) * rstd * w[c]     + b[c];
  float y1 = (x1 - mean) * rstd * w[c + 1] + b[c + 1];
  u32t ov = ((u32t)f2bfbits(y1) << 16) | (u32t)f2bfbits(y0);
  *(u32t*)((u16t*)o + (size_t)t * 128 + c) = ov;
}

// ---------------------------------------------------------------------------
// MFMA GEMM: C[M,N] = A[M,K](bf16) @ W[N,K](bf16)^T + bias(fp32).
// 128x64 block tile, BK=64, 256 threads (4 waves), each wave 32x64 via
// 2x4 mfma_f32_16x16x32_bf16 frags. fp32 accumulation.
// Layouts (guide-verified): A-frag lane: m=lane&15, k=quad*8+j (contig 8 bf16)
//                           B-frag from W rows: n=lane&15, k=quad*8+j
//                           C/D: col=lane&15, row=quad*4+reg
// MODE 0: +bias -> bf16                         (qkv)
// MODE 1: +bias +window-reverse +resX(fp32) -> bf16  (proj)
// MODE 2: +bias +exact GELU -> bf16             (fc1)
// MODE 3: +bias +resB2(bf16) -> fp32 out        (fc2, final)
// ---------------------------------------------------------------------------
template <int MODE>
__global__ __launch_bounds__(256) void gemm_mfma_k(
    const bf16* __restrict__ A, const bf16* __restrict__ W,
    const float* __restrict__ bias, const float* __restrict__ resX,
    const bf16* __restrict__ resB2, bf16* __restrict__ outB,
    float* __restrict__ outF, int N, int K)
{
  __shared__ short As[128 * 64];
  __shared__ short Bs[64 * 64];
  const int tid = threadIdx.x;
  const int rowBase = blockIdx.y << 7;   // 128-row tile
  const int colBase = blockIdx.x << 6;   // 64-col tile
  const int wv = tid >> 6, lane = tid & 63;
  const int q = lane >> 4, r16 = lane & 15;
  const int mB = wv << 5;                // wave's 32-row sub-tile

  f32x4_t acc[2][4];
#pragma unroll
  for (int i = 0; i < 2; i++)
#pragma unroll
    for (int j = 0; j < 4; j++) acc[i][j] = (f32x4_t){0.f, 0.f, 0.f, 0.f};

  for (int k0 = 0; k0 < K; k0 += 64) {
    // stage A-tile (128x64) : 1024 uint4, 4 per thread
#pragma unroll
    for (int t = 0; t < 4; t++) {
      int flat = tid + (t << 8);
      int row = flat >> 3, c8 = (flat & 7) << 3;
      *(uint4*)&As[(row << 6) + c8] =
          *(const uint4*)((const u16t*)A + (size_t)(rowBase + row) * K + k0 + c8);
    }
    // stage B-tile (64x64): 512 uint4, 2 per thread
#pragma unroll
    for (int t = 0; t < 2; t++) {
      int flat = tid + (t << 8);
      int row = flat >> 3, c8 = (flat & 7) << 3;
      *(uint4*)&Bs[(row << 6) + c8] =
          *(const uint4*)((const u16t*)W + (size_t)(colBase + row) * K + k0 + c8);
    }
    __syncthreads();
#pragma unroll
    for (int ks = 0; ks < 2; ks++) {
      bf16x8_t af[2], bfr[4];
#pragma unroll
      for (int mt = 0; mt < 2; mt++)
        af[mt] = *(const bf16x8_t*)&As[((mB + (mt << 4) + r16) << 6) + (ks << 5) + (q << 3)];
#pragma unroll
      for (int nt = 0; nt < 4; nt++)
        bfr[nt] = *(const bf16x8_t*)&Bs[(((nt << 4) + r16) << 6) + (ks << 5) + (q << 3)];
#pragma unroll
      for (int mt = 0; mt < 2; mt++)
#pragma unroll
        for (int nt = 0; nt < 4; nt++)
          acc[mt][nt] = __builtin_amdgcn_mfma_f32_16x16x32_bf16(
              af[mt], bfr[nt], acc[mt][nt], 0, 0, 0);
    }
    __syncthreads();
  }

  float bv[4];
#pragma unroll
  for (int nt = 0; nt < 4; nt++) bv[nt] = bias[colBase + (nt << 4) + r16];

#pragma unroll
  for (int mt = 0; mt < 2; mt++) {
#pragma unroll
    for (int reg = 0; reg < 4; reg++) {
      int grow = rowBase + mB + (mt << 4) + (q << 2) + reg;
      if (MODE == 1) {
        int nw = grow / NTOK, n = grow - nw * NTOK;
        int wq = nw & 7, hq = (nw >> 3) & 7, dq = (nw >> 6) & 3, bb = nw >> 8;
        int wr = n % 7; int q7 = n / 7; int hr = q7 % 7, dr = q7 / 7;
        int tt = ((bb * 8 + dq * 2 + dr) * 56 + hq * 7 + hr) * 56 + wq * 7 + wr;
        size_t ob = (size_t)tt * 128;
#pragma unroll
        for (int nt = 0; nt < 4; nt++) {
          int gcol = colBase + (nt << 4) + r16;
          outB[ob + gcol] = f2bf(acc[mt][nt][reg] + bv[nt] + resX[ob + gcol]);
        }
      } else if (MODE == 2) {
        size_t ob = (size_t)grow * N;
#pragma unroll
        for (int nt = 0; nt < 4; nt++) {
          int gcol = colBase + (nt << 4) + r16;
          float u = acc[mt][nt][reg] + bv[nt];
          float g = 0.5f * u * (1.0f + erff(u * 0.70710678118654752f));
          outB[ob + gcol] = f2bf(g);
        }
      } else if (MODE == 3) {
        size_t ob = (size_t)grow * N;
#pragma unroll
        for (int nt = 0; nt < 4; nt++) {
          int gcol = colBase + (nt << 4) + r16;
          outF[ob + gcol] = acc[mt][nt][reg] + bv[nt] + bf2f(resB2[ob + gcol]);
        }
      } else {
        size_t ob = (size_t)grow * N;
#pragma unroll
        for (int nt = 0; nt < 4; nt++) {
          int gcol = colBase + (nt << 4) + r16;
          outB[ob + gcol] = f2bf(acc[mt][nt][reg] + bv[nt]);
        }
      }
    }
  }
}

// ---------------------------------------------------------------------------
// Fused windowed attention. One block per (window, head). q,k,v in LDS.
// Each wave owns 2 query rows per iteration; ps scratch is wave-private so
// NO barriers in the main loop (same-wave LDS RAW is hw-ordered).
// ---------------------------------------------------------------------------
__global__ __launch_bounds__(256) void attn_k(
    const bf16* __restrict__ qkv, const float* __restrict__ btab,
    const int* __restrict__ relidx, bf16* __restrict__ out)
{
  __shared__ float qs[NTOK][34];   // pad 34: float2 8B-aligned, 2-way banks
  __shared__ float ks[NTOK][34];
  __shared__ float vs[NTOK][33];
  __shared__ float ps[8][104];
  const int nw = blockIdx.x, head = blockIdx.y;
  const int tid = threadIdx.x;
  const float scale = 0.17677669529663687f;  // 32^-0.5

  for (int idx = tid; idx < NTOK * 16; idx += 256) {
    int r = idx >> 4, d2 = (idx & 15) << 1;
    const u16t* base = (const u16t*)qkv + (size_t)(nw * NTOK + r) * 384 + head * 32 + d2;
    u32t uq = *(const u32t*)(base);
    u32t uk = *(const u32t*)(base + 128);
    u32t uv = *(const u32t*)(base + 256);
    qs[r][d2] = bflo(uq) * scale; qs[r][d2 + 1] = bfhi(uq) * scale;
    ks[r][d2] = bflo(uk);         ks[r][d2 + 1] = bfhi(uk);
    vs[r][d2] = bflo(uv);         vs[r][d2 + 1] = bfhi(uv);
  }
  __syncthreads();

  const int wv = tid >> 6, lane = tid & 63;
  const int w2 = wv << 1;
  const int j0 = lane;
  const bool vld1 = lane < 34;            // lane+64 < 98
  const int j1 = vld1 ? lane + 64 : NTOK - 1;
  const int dd = lane & 31, half = lane >> 5;

  for (int it = 0; it < 13; it++) {
    int i0 = (it << 3) + w2, i1 = i0 + 1;
    bool act0 = i0 < NTOK, act1 = i1 < NTOK;
    int ic0 = act0 ? i0 : NTOK - 1;
    int ic1 = act1 ? i1 : NTOK - 1;
    float s00 = 0.f, s01 = 0.f, s10 = 0.f, s11 = 0.f;
#pragma unroll
    for (int d2 = 0; d2 < 16; d2++) {
      float2 q0v = *(const float2*)&qs[ic0][d2 << 1];
      float2 q1v = *(const float2*)&qs[ic1][d2 << 1];
      float2 k0v = *(const float2*)&ks[j0][d2 << 1];
      float2 k1v = *(const float2*)&ks[j1][d2 << 1];
      s00 += q0v.x * k0v.x + q0v.y * k0v.y;
      s01 += q0v.x * k1v.x + q0v.y * k1v.y;
      s10 += q1v.x * k0v.x + q1v.y * k0v.y;
      s11 += q1v.x * k1v.x + q1v.y * k1v.y;
    }
    s00 += btab[relidx[ic0 * NTOK + j0] * NHEAD + head];
    s10 += btab[relidx[ic1 * NTOK + j0] * NHEAD + head];
    float b01 = btab[relidx[ic0 * NTOK + j1] * NHEAD + head];
    float b11 = btab[relidx[ic1 * NTOK + j1] * NHEAD + head];
    s01 = vld1 ? (s01 + b01) : -1.0e30f;
    s11 = vld1 ? (s11 + b11) : -1.0e30f;
    // row i0 softmax
    float m0 = fmaxf(s00, s01), m1 = fmaxf(s10, s11);
#pragma unroll
    for (int d = 32; d; d >>= 1) {
      m0 = fmaxf(m0, __shfl_xor(m0, d));
      m1 = fmaxf(m1, __shfl_xor(m1, d));
    }
    float e00 = __expf(s00 - m0);
    float e01 = vld1 ? __expf(s01 - m0) : 0.f;
    float e10 = __expf(s10 - m1);
    float e11 = vld1 ? __expf(s11 - m1) : 0.f;
    float sum0 = e00 + e01, sum1 = e10 + e11;
#pragma unroll
    for (int d = 32; d; d >>= 1) {
      sum0 += __shfl_xor(sum0, d);
      sum1 += __shfl_xor(sum1, d);
    }
    float inv0 = 1.f / sum0, inv1 = 1.f / sum1;
    ps[w2][j0] = e00 * inv0;
    ps[w2 + 1][j0] = e10 * inv1;
    if (vld1) {
      ps[w2][lane + 64] = e01 * inv0;
      ps[w2 + 1][lane + 64] = e11 * inv1;
    }
    // PV (same-wave LDS RAW -> no barrier needed)
    float a0 = 0.f, a1 = 0.f;
#pragma unroll
    for (int jj = 0; jj < 49; jj++) {
      int j = half * 49 + jj;
      float pv = vs[j][dd];
      a0 += ps[w2][j] * pv;
      a1 += ps[w2 + 1][j] * pv;
    }
    a0 += __shfl_down(a0, 32);
    a1 += __shfl_down(a1, 32);
    if (lane < 32) {
      if (act0) out[(size_t)(nw * NTOK + i0) * 128 + head * 32 + dd] = f2bf(a0);
      if (act1) out[(size_t)(nw * NTOK + i1) * 128 + head * 32 + dd] = f2bf(a1);
    }
  }
}

// ---------------------------------------------------------------------------
extern "C" void kernel_launch(void* const* d_in, const int* in_sizes, int n_in,
                              void* d_out, int out_size, void* d_ws, size_t ws_size,
                              hipStream_t stream) {
  const float* x      = (const float*)d_in[0];
  const float* n1w    = (const float*)d_in[1];
  const float* n1b    = (const float*)d_in[2];
  const float* qkv_w  = (const float*)d_in[3];
  const float* qkv_b  = (const float*)d_in[4];
  const float* btab   = (const float*)d_in[5];
  const float* proj_w = (const float*)d_in[6];
  const float* proj_b = (const float*)d_in[7];
  const float* n2w    = (const float*)d_in[8];
  const float* n2b    = (const float*)d_in[9];
  const float* fc1_w  = (const float*)d_in[10];
  const float* fc1_b  = (const float*)d_in[11];
  const float* fc2_w  = (const float*)d_in[12];
  const float* fc2_b  = (const float*)d_in[13];
  const int*   relidx = (const int*)d_in[14];

  // Buffer plan (A = 50176*128*2 B):
  //   d_out doubles as scratch: xw = attn = d_out[0,A) (dead before final out)
  //   ws: [0,3A) qkv -> x2(ws[0,A)) / xn2(ws[A,2A)) / hmid(ws[2A,3A))
  //       [3A, 3A+384KB) bf16 weights
  const size_t Asz = (size_t)TOK * 128 * 2;
  char* ws = (char*)d_ws;
  bf16* xw    = (bf16*)d_out;
  bf16* attn  = (bf16*)d_out;
  bf16* qkv   = (bf16*)(ws);
  bf16* x2    = (bf16*)(ws);
  bf16* xn2   = (bf16*)(ws + Asz);
  bf16* hmid  = (bf16*)(ws + 2 * Asz);
  bf16* wbf   = (bf16*)(ws + 3 * Asz);
  bf16* qkvw16 = wbf;                // 49152
  bf16* projw16 = wbf + 49152;       // 16384
  bf16* fc1w16  = wbf + 65536;       // 65536
  bf16* fc2w16  = wbf + 131072;      // 65536
  float* out  = (float*)d_out;

  // 0. weight conversion fp32 -> bf16
  cvt_k<<<192, 256, 0, stream>>>(qkv_w, qkvw16, 49152);
  cvt_k<<<64, 256, 0, stream>>>(proj_w, projw16, 16384);
  cvt_k<<<256, 256, 0, stream>>>(fc1_w, fc1w16, 65536);
  cvt_k<<<256, 256, 0, stream>>>(fc2_w, fc2w16, 65536);
  // 1. LN1 + window partition
  ln1_k<<<TOK / 4, 256, 0, stream>>>(x, n1w, n1b, xw);
  // 2. QKV: (50176,128) @ (384,128)^T
  gemm_mfma_k<0><<<dim3(6, TOK / 128), 256, 0, stream>>>(
      xw, qkvw16, qkv_b, nullptr, nullptr, qkv, nullptr, 384, 128);
  // 3. windowed attention
  attn_k<<<dim3(NWIN, NHEAD), 256, 0, stream>>>(qkv, btab, relidx, attn);
  // 4. proj + window reverse + residual(x fp32) -> x2 bf16 (token order)
  gemm_mfma_k<1><<<dim3(2, TOK / 128), 256, 0, stream>>>(
      attn, projw16, proj_b, x, nullptr, x2, nullptr, 128, 128);
  // 5. LN2
  ln2_k<<<TOK / 4, 256, 0, stream>>>(x2, n2w, n2b, xn2);
  // 6/7. MLP in 4 token chunks (hmid reuse keeps ws at 3A)
  const int MC = TOK / 4;  // 12544 rows per chunk
  for (int c = 0; c < 4; c++) {
    gemm_mfma_k<2><<<dim3(8, MC / 128), 256, 0, stream>>>(
        xn2 + (size_t)c * MC * 128, fc1w16, fc1_b, nullptr, nullptr,
        hmid, nullptr, 512, 128);
    gemm_mfma_k<3><<<dim3(2, MC / 128), 256, 0, stream>>>(
        hmid, fc2w16, fc2_b, nullptr, x2 + (size_t)c * MC * 128,
        nullptr, out + (size_t)c * MC * 128, 128, 512);
  }
}

// Round 5
// 332.004 us; speedup vs baseline: 2.3619x; 1.2080x over previous
//
#include <hip/hip_runtime.h>
#include <hip/hip_bf16.h>

typedef __hip_bfloat16 bf16;
typedef unsigned short u16t;
typedef unsigned int u32t;
typedef __attribute__((ext_vector_type(8))) short bf16x8_t;
typedef __attribute__((ext_vector_type(4))) float f32x4_t;

#define DEVI static __device__ __forceinline__

DEVI float u2f(u32t bits) { union { u32t u; float f; } v; v.u = bits; return v.f; }
DEVI float bflo(u32t u) { return u2f((u & 0xffffu) << 16); }
DEVI float bfhi(u32t u) { return u2f(u & 0xffff0000u); }
DEVI float bf2f(bf16 h) { return __bfloat162float(h); }
DEVI bf16 f2bf(float f) { return __float2bfloat16(f); }
DEVI u16t f2bfbits(float f) {
  bf16 h = __float2bfloat16(f);
  union { bf16 h; u16t u; } v; v.h = h; return v.u;
}

// Problem constants: x (2,8,56,56,128); windows (2,7,7) -> N=98; NW=512
#define TOK   50176
#define NWIN  512
#define NTOK  98
#define NHEAD 4
#define HDIM  32

// ---------------------------------------------------------------------------
// fp32 -> bf16 weight conversion
// ---------------------------------------------------------------------------
__global__ __launch_bounds__(256) void cvt_k(const float* __restrict__ s,
                                             bf16* __restrict__ d, int n) {
  int i = blockIdx.x * 256 + threadIdx.x;
  if (i < n) d[i] = f2bf(s[i]);
}

// ---------------------------------------------------------------------------
// Bias matrix precompute: Bmat[h][i][j] = btab[relidx[i*98+j]*4 + h]
// ---------------------------------------------------------------------------
__global__ __launch_bounds__(256) void bias_k(const float* __restrict__ btab,
                                              const int* __restrict__ relidx,
                                              float* __restrict__ Bmat) {
  int idx = blockIdx.x * 256 + threadIdx.x;
  if (idx < NTOK * NTOK) {
    int r = relidx[idx] * NHEAD;
#pragma unroll
    for (int h = 0; h < NHEAD; h++)
      Bmat[h * NTOK * NTOK + idx] = btab[r + h];
  }
}

// ---------------------------------------------------------------------------
// LN1 (fp32 input, token order) + window partition -> bf16
// ---------------------------------------------------------------------------
__global__ __launch_bounds__(256) void ln1_k(
    const float* __restrict__ x, const float* __restrict__ w,
    const float* __restrict__ b, bf16* __restrict__ o)
{
  const int wave = threadIdx.x >> 6, lane = threadIdx.x & 63;
  const int t = blockIdx.x * 4 + wave;
  const int c = lane << 1;
  float2 xv = *(const float2*)(x + (size_t)t * 128 + c);
  float x0 = xv.x, x1 = xv.y;
  float s = x0 + x1, ss = x0 * x0 + x1 * x1;
#pragma unroll
  for (int m = 32; m; m >>= 1) { s += __shfl_xor(s, m); ss += __shfl_xor(ss, m); }
  float mean = s * 0.0078125f;
  float var = ss * 0.0078125f - mean * mean;
  float rstd = rsqrtf(var + 1e-5f);
  float y0 = (x0 - mean) * rstd * w[c]     + b[c];
  float y1 = (x1 - mean) * rstd * w[c + 1] + b[c + 1];
  int wi = t % 56; int r = t / 56;
  int hi_ = r % 56; r /= 56;
  int di = r & 7; int bi = r >> 3;
  int nw = ((bi * 4 + (di >> 1)) * 8 + hi_ / 7) * 8 + wi / 7;
  int n  = ((di & 1) * 7 + hi_ % 7) * 7 + wi % 7;
  u32t ov = ((u32t)f2bfbits(y1) << 16) | (u32t)f2bfbits(y0);
  *(u32t*)((u16t*)o + (size_t)(nw * NTOK + n) * 128 + c) = ov;
}

// ---------------------------------------------------------------------------
// LN2 (bf16 input, token order) -> bf16
// ---------------------------------------------------------------------------
__global__ __launch_bounds__(256) void ln2_k(
    const bf16* __restrict__ x, const float* __restrict__ w,
    const float* __restrict__ b, bf16* __restrict__ o)
{
  const int wave = threadIdx.x >> 6, lane = threadIdx.x & 63;
  const int t = blockIdx.x * 4 + wave;
  const int c = lane << 1;
  u32t u = *(const u32t*)((const u16t*)x + (size_t)t * 128 + c);
  float x0 = bflo(u), x1 = bfhi(u);
  float s = x0 + x1, ss = x0 * x0 + x1 * x1;
#pragma unroll
  for (int m = 32; m; m >>= 1) { s += __shfl_xor(s, m); ss += __shfl_xor(ss, m); }
  float mean = s * 0.0078125f;
  float var = ss * 0.0078125f - mean * mean;
  float rstd = rsqrtf(var + 1e-5f);
  float y0 = (x0 - mean) * rstd * w[c]     + b[c];
  float y1 = (x1 - mean) * rstd * w[c + 1] + b[c + 1];
  u32t ov = ((u32t)f2bfbits(y1) << 16) | (u32t)f2bfbits(y0);
  *(u32t*)((u16t*)o + (size_t)t * 128 + c) = ov;
}

// ---------------------------------------------------------------------------
// MFMA GEMM: C[M,N] = A[M,K](bf16) @ W[N,K](bf16)^T + bias(fp32).
// 128x64 tile, BK=64, 4 waves, 2x4 mfma_f32_16x16x32_bf16 frags per wave.
// LDS stride 72 (=144B, 16B-aligned) -> 2-way banks (free) on frag reads.
// MODE 0: +bias -> bf16; 1: +bias+winrev+resX(f32) -> bf16;
// MODE 2: +bias+GELU -> bf16; 3: +bias+resB2(bf16) -> fp32 (final)
// ---------------------------------------------------------------------------
#define LSTR 72
template <int MODE>
__global__ __launch_bounds__(256) void gemm_mfma_k(
    const bf16* __restrict__ A, const bf16* __restrict__ W,
    const float* __restrict__ bias, const float* __restrict__ resX,
    const bf16* __restrict__ resB2, bf16* __restrict__ outB,
    float* __restrict__ outF, int N, int K)
{
  __shared__ short As[128 * LSTR];
  __shared__ short Bs[64 * LSTR];
  const int tid = threadIdx.x;
  const int rowBase = blockIdx.y << 7;
  const int colBase = blockIdx.x << 6;
  const int wv = tid >> 6, lane = tid & 63;
  const int q = lane >> 4, r16 = lane & 15;
  const int mB = wv << 5;

  f32x4_t acc[2][4];
#pragma unroll
  for (int i = 0; i < 2; i++)
#pragma unroll
    for (int j = 0; j < 4; j++) acc[i][j] = (f32x4_t){0.f, 0.f, 0.f, 0.f};

  for (int k0 = 0; k0 < K; k0 += 64) {
#pragma unroll
    for (int t = 0; t < 4; t++) {
      int flat = tid + (t << 8);
      int row = flat >> 3, c8 = (flat & 7) << 3;
      *(uint4*)&As[row * LSTR + c8] =
          *(const uint4*)((const u16t*)A + (size_t)(rowBase + row) * K + k0 + c8);
    }
#pragma unroll
    for (int t = 0; t < 2; t++) {
      int flat = tid + (t << 8);
      int row = flat >> 3, c8 = (flat & 7) << 3;
      *(uint4*)&Bs[row * LSTR + c8] =
          *(const uint4*)((const u16t*)W + (size_t)(colBase + row) * K + k0 + c8);
    }
    __syncthreads();
#pragma unroll
    for (int ks = 0; ks < 2; ks++) {
      bf16x8_t af[2], bfr[4];
#pragma unroll
      for (int mt = 0; mt < 2; mt++)
        af[mt] = *(const bf16x8_t*)&As[(mB + (mt << 4) + r16) * LSTR + (ks << 5) + (q << 3)];
#pragma unroll
      for (int nt = 0; nt < 4; nt++)
        bfr[nt] = *(const bf16x8_t*)&Bs[((nt << 4) + r16) * LSTR + (ks << 5) + (q << 3)];
#pragma unroll
      for (int mt = 0; mt < 2; mt++)
#pragma unroll
        for (int nt = 0; nt < 4; nt++)
          acc[mt][nt] = __builtin_amdgcn_mfma_f32_16x16x32_bf16(
              af[mt], bfr[nt], acc[mt][nt], 0, 0, 0);
    }
    __syncthreads();
  }

  float bv[4];
#pragma unroll
  for (int nt = 0; nt < 4; nt++) bv[nt] = bias[colBase + (nt << 4) + r16];

#pragma unroll
  for (int mt = 0; mt < 2; mt++) {
#pragma unroll
    for (int reg = 0; reg < 4; reg++) {
      int grow = rowBase + mB + (mt << 4) + (q << 2) + reg;
      if (MODE == 1) {
        int nw = grow / NTOK, n = grow - nw * NTOK;
        int wq = nw & 7, hq = (nw >> 3) & 7, dq = (nw >> 6) & 3, bb = nw >> 8;
        int wr = n % 7; int q7 = n / 7; int hr = q7 % 7, dr = q7 / 7;
        int tt = ((bb * 8 + dq * 2 + dr) * 56 + hq * 7 + hr) * 56 + wq * 7 + wr;
        size_t ob = (size_t)tt * 128;
#pragma unroll
        for (int nt = 0; nt < 4; nt++) {
          int gcol = colBase + (nt << 4) + r16;
          outB[ob + gcol] = f2bf(acc[mt][nt][reg] + bv[nt] + resX[ob + gcol]);
        }
      } else if (MODE == 2) {
        size_t ob = (size_t)grow * N;
#pragma unroll
        for (int nt = 0; nt < 4; nt++) {
          int gcol = colBase + (nt << 4) + r16;
          float u = acc[mt][nt][reg] + bv[nt];
          float g = 0.5f * u * (1.0f + erff(u * 0.70710678118654752f));
          outB[ob + gcol] = f2bf(g);
        }
      } else if (MODE == 3) {
        size_t ob = (size_t)grow * N;
#pragma unroll
        for (int nt = 0; nt < 4; nt++) {
          int gcol = colBase + (nt << 4) + r16;
          outF[ob + gcol] = acc[mt][nt][reg] + bv[nt] + bf2f(resB2[ob + gcol]);
        }
      } else {
        size_t ob = (size_t)grow * N;
#pragma unroll
        for (int nt = 0; nt < 4; nt++) {
          int gcol = colBase + (nt << 4) + r16;
          outB[ob + gcol] = f2bf(acc[mt][nt][reg] + bv[nt]);
        }
      }
    }
  }
}

// ---------------------------------------------------------------------------
// MFMA windowed attention. One block (4 waves) per (window, head).
// 98 -> 7 tiles of 16. Wave w owns m-tiles {w, w+4}. Q/K frags straight from
// global; softmax in registers (shfl over 16-lane groups); P via LDS (bf16,
// stride 136, same-wave RAW so no barrier); V transposed in LDS for PV.
// ---------------------------------------------------------------------------
#define PSTR 136
__global__ __launch_bounds__(256) void attn_mfma_k(
    const bf16* __restrict__ qkv, const float* __restrict__ Bmat,
    bf16* __restrict__ out)
{
  __shared__ short Vt[32 * PSTR];    // V^T [d][j], zero-padded j>=98
  __shared__ short Ps[112 * PSTR];   // P [i][j] bf16, cols 112..135 zeroed
  const int nw = blockIdx.x, h = blockIdx.y;
  const int tid = threadIdx.x;
  const int wv = tid >> 6, lane = tid & 63;
  const int q = lane >> 4, r16 = lane & 15;
  const float scale = 0.17677669529663687f;  // 32^-0.5

  // zero-fill Vt cols [98,136)
  for (int idx = tid; idx < 32 * 38; idx += 256) {
    int d = idx / 38, j = 98 + idx % 38;
    Vt[d * PSTR + j] = 0;
  }
  // zero-fill Ps cols [112,136) (prevents 0*NaN in PV k-tile 3)
  for (int idx = tid; idx < 112 * 12; idx += 256) {
    int r = idx / 12, c = (idx % 12) << 1;
    *(u32t*)&Ps[r * PSTR + 112 + c] = 0;
  }
  // stage V transposed
  for (int idx = tid; idx < NTOK * 16; idx += 256) {
    int j = idx >> 4, d2 = (idx & 15) << 1;
    u32t uv = *(const u32t*)((const u16t*)qkv +
                             (size_t)(nw * NTOK + j) * 384 + 256 + h * 32 + d2);
    Vt[d2 * PSTR + j] = (short)(uv & 0xffffu);
    Vt[(d2 + 1) * PSTR + j] = (short)(uv >> 16);
  }
  __syncthreads();

  const int mt0 = wv;
  const bool has2 = (wv + 4) < 7;
  const int mt1 = has2 ? wv + 4 : wv;

  // Q A-frags from global (rows clamped; padded rows discarded later)
  int i0 = mt0 * 16 + r16; if (i0 > NTOK - 1) i0 = NTOK - 1;
  int i1 = mt1 * 16 + r16; if (i1 > NTOK - 1) i1 = NTOK - 1;
  bf16x8_t aq0 = *(const bf16x8_t*)((const u16t*)qkv +
      (size_t)(nw * NTOK + i0) * 384 + h * 32 + (q << 3));
  bf16x8_t aq1 = *(const bf16x8_t*)((const u16t*)qkv +
      (size_t)(nw * NTOK + i1) * 384 + h * 32 + (q << 3));

  // QK^T: 7 n-tiles, K B-frags from global
  f32x4_t sc[2][7];
#pragma unroll
  for (int nt = 0; nt < 7; nt++) {
    int j = (nt << 4) + r16; if (j > NTOK - 1) j = NTOK - 1;
    bf16x8_t bk = *(const bf16x8_t*)((const u16t*)qkv +
        (size_t)(nw * NTOK + j) * 384 + 128 + h * 32 + (q << 3));
    sc[0][nt] = __builtin_amdgcn_mfma_f32_16x16x32_bf16(
        aq0, bk, (f32x4_t){0.f, 0.f, 0.f, 0.f}, 0, 0, 0);
    sc[1][nt] = __builtin_amdgcn_mfma_f32_16x16x32_bf16(
        aq1, bk, (f32x4_t){0.f, 0.f, 0.f, 0.f}, 0, 0, 0);
  }

  // softmax in registers (C-layout: col=r16 within n-tile, row=q*4+reg)
  const float* Bh = Bmat + h * (NTOK * NTOK);
#pragma unroll
  for (int sel = 0; sel < 2; sel++) {
    if (sel == 1 && !has2) break;
    int mtile = sel ? mt1 : mt0;
#pragma unroll
    for (int reg = 0; reg < 4; reg++) {
      int i = mtile * 16 + (q << 2) + reg;
      float s[7];
      float m = -3.0e38f;
#pragma unroll
      for (int nt = 0; nt < 7; nt++) {
        int j = (nt << 4) + r16;
        float v = sc[sel][nt][reg] * scale;
        v = (i < NTOK && j < NTOK) ? v + Bh[i * NTOK + j] : -1.0e30f;
        s[nt] = v;
        m = fmaxf(m, v);
      }
#pragma unroll
      for (int d = 8; d; d >>= 1) m = fmaxf(m, __shfl_xor(m, d));
      float sum = 0.f;
#pragma unroll
      for (int nt = 0; nt < 7; nt++) { s[nt] = __expf(s[nt] - m); sum += s[nt]; }
#pragma unroll
      for (int d = 8; d; d >>= 1) sum += __shfl_xor(sum, d);
      float inv = 1.f / sum;
#pragma unroll
      for (int nt = 0; nt < 7; nt++)
        Ps[(mtile * 16 + (q << 2) + reg) * PSTR + (nt << 4) + r16] =
            (short)f2bfbits(s[nt] * inv);
    }
  }

  // PV: O = P @ Vt^T. Same-wave LDS RAW (Ps rows owned by this wave) -> no
  // barrier. 4 k-tiles of 32 cover j in [0,128) (cols>=98 are exactly 0).
#pragma unroll
  for (int sel = 0; sel < 2; sel++) {
    if (sel == 1 && !has2) break;
    int mtile = sel ? mt1 : mt0;
    f32x4_t o0 = {0.f, 0.f, 0.f, 0.f}, o1 = {0.f, 0.f, 0.f, 0.f};
#pragma unroll
    for (int kt = 0; kt < 4; kt++) {
      bf16x8_t ap = *(const bf16x8_t*)&Ps[(mtile * 16 + r16) * PSTR + (kt << 5) + (q << 3)];
      bf16x8_t bv0 = *(const bf16x8_t*)&Vt[r16 * PSTR + (kt << 5) + (q << 3)];
      bf16x8_t bv1 = *(const bf16x8_t*)&Vt[(16 + r16) * PSTR + (kt << 5) + (q << 3)];
      o0 = __builtin_amdgcn_mfma_f32_16x16x32_bf16(ap, bv0, o0, 0, 0, 0);
      o1 = __builtin_amdgcn_mfma_f32_16x16x32_bf16(ap, bv1, o1, 0, 0, 0);
    }
#pragma unroll
    for (int reg = 0; reg < 4; reg++) {
      int i = mtile * 16 + (q << 2) + reg;
      if (i < NTOK) {
        size_t ob = (size_t)(nw * NTOK + i) * 128 + h * 32;
        out[ob + r16] = f2bf(o0[reg]);
        out[ob + 16 + r16] = f2bf(o1[reg]);
      }
    }
  }
}

// ---------------------------------------------------------------------------
extern "C" void kernel_launch(void* const* d_in, const int* in_sizes, int n_in,
                              void* d_out, int out_size, void* d_ws, size_t ws_size,
                              hipStream_t stream) {
  const float* x      = (const float*)d_in[0];
  const float* n1w    = (const float*)d_in[1];
  const float* n1b    = (const float*)d_in[2];
  const float* qkv_w  = (const float*)d_in[3];
  const float* qkv_b  = (const float*)d_in[4];
  const float* btab   = (const float*)d_in[5];
  const float* proj_w = (const float*)d_in[6];
  const float* proj_b = (const float*)d_in[7];
  const float* n2w    = (const float*)d_in[8];
  const float* n2b    = (const float*)d_in[9];
  const float* fc1_w  = (const float*)d_in[10];
  const float* fc1_b  = (const float*)d_in[11];
  const float* fc2_w  = (const float*)d_in[12];
  const float* fc2_b  = (const float*)d_in[13];
  const int*   relidx = (const int*)d_in[14];

  // Buffer plan (A = 50176*128*2 B):
  //   d_out doubles as scratch: xw = attn = d_out[0,A)
  //   ws: [0,3A) qkv -> x2(ws[0,A)) / xn2(ws[A,2A)) / hmid(ws[2A,3A))
  //       [3A, +384KB) bf16 weights; then Bmat fp32 (154KB)
  const size_t Asz = (size_t)TOK * 128 * 2;
  char* ws = (char*)d_ws;
  bf16* xw    = (bf16*)d_out;
  bf16* attn  = (bf16*)d_out;
  bf16* qkv   = (bf16*)(ws);
  bf16* x2    = (bf16*)(ws);
  bf16* xn2   = (bf16*)(ws + Asz);
  bf16* hmid  = (bf16*)(ws + 2 * Asz);
  bf16* wbf   = (bf16*)(ws + 3 * Asz);
  bf16* qkvw16  = wbf;               // 49152
  bf16* projw16 = wbf + 49152;       // 16384
  bf16* fc1w16  = wbf + 65536;       // 65536
  bf16* fc2w16  = wbf + 131072;      // 65536
  float* Bmat = (float*)(ws + 3 * Asz + 393216);  // 4*98*98 fp32
  float* out  = (float*)d_out;

  // 0. weight conversion + bias matrix
  cvt_k<<<192, 256, 0, stream>>>(qkv_w, qkvw16, 49152);
  cvt_k<<<64, 256, 0, stream>>>(proj_w, projw16, 16384);
  cvt_k<<<256, 256, 0, stream>>>(fc1_w, fc1w16, 65536);
  cvt_k<<<256, 256, 0, stream>>>(fc2_w, fc2w16, 65536);
  bias_k<<<38, 256, 0, stream>>>(btab, relidx, Bmat);
  // 1. LN1 + window partition
  ln1_k<<<TOK / 4, 256, 0, stream>>>(x, n1w, n1b, xw);
  // 2. QKV: (50176,128) @ (384,128)^T
  gemm_mfma_k<0><<<dim3(6, TOK / 128), 256, 0, stream>>>(
      xw, qkvw16, qkv_b, nullptr, nullptr, qkv, nullptr, 384, 128);
  // 3. MFMA windowed attention
  attn_mfma_k<<<dim3(NWIN, NHEAD), 256, 0, stream>>>(qkv, Bmat, attn);
  // 4. proj + window reverse + residual(x fp32) -> x2 bf16 (token order)
  gemm_mfma_k<1><<<dim3(2, TOK / 128), 256, 0, stream>>>(
      attn, projw16, proj_b, x, nullptr, x2, nullptr, 128, 128);
  // 5. LN2
  ln2_k<<<TOK / 4, 256, 0, stream>>>(x2, n2w, n2b, xn2);
  // 6/7. MLP in 4 token chunks (hmid reuse keeps ws at 3A)
  const int MC = TOK / 4;  // 12544 rows per chunk
  for (int c = 0; c < 4; c++) {
    gemm_mfma_k<2><<<dim3(8, MC / 128), 256, 0, stream>>>(
        xn2 + (size_t)c * MC * 128, fc1w16, fc1_b, nullptr, nullptr,
        hmid, nullptr, 512, 128);
    gemm_mfma_k<3><<<dim3(2, MC / 128), 256, 0, stream>>>(
        hmid, fc2w16, fc2_b, nullptr, x2 + (size_t)c * MC * 128,
        nullptr, out + (size_t)c * MC * 128, 128, 512);
  }
}